// Round 3
// baseline (281.166 us; speedup 1.0000x reference)
//
#include <hip/hip_runtime.h>

// Problem constants (match reference)
#define BB 4096
#define DD 8192
#define KK 5
#define GS 40
#define MAXIT 3
#define EFF 17            // 4*(KK-1)+1 composed taps
#define D4 (DD/4)         // float4 elements per row = 2048

typedef float vf4 __attribute__((ext_vector_type(4)));  // native vec for NT store

__device__ __forceinline__ int iabs(int a) { return a < 0 ? -a : a; }

// ---------------------------------------------------------------------------
// Single fused kernel, one block per row, NO LDS, NO barrier.
//  - each wave redundantly scans g[4096] (16 KB, L2-hot) + butterfly reduce
//    to get batch-wide max_it -> removes the k_max_it kernel + dependency
//  - compose the effective 17-tap circular kernel per row in registers
//  - out[d] = sum_m E[m] * x[(d+m-8) mod D], reading x directly from global
//    (5x read amplification absorbed by L1/L2; HBM sees x once)
//  - nontemporal float4 stores: out is write-once, keep x resident in LLC
// ---------------------------------------------------------------------------
__global__ __launch_bounds__(256) void k_fused(const float* __restrict__ x,
                                               const int* __restrict__ g,
                                               const float* __restrict__ kernels,
                                               float* __restrict__ out) {
    const int b    = blockIdx.x;
    const int t    = threadIdx.x;
    const int lane = t & 63;

    // --- per-wave scan of g for batch max|g| (no cross-wave sync needed) ---
    const int4* g4 = (const int4*)g;   // 1024 int4
    int gm = 0;
#pragma unroll
    for (int i = 0; i < 16; ++i) {
        int4 v = g4[lane + 64 * i];
        gm = max(gm, max(max(iabs(v.x), iabs(v.y)), max(iabs(v.z), iabs(v.w))));
    }
#pragma unroll
    for (int off = 32; off > 0; off >>= 1)
        gm = max(gm, __shfl_xor(gm, off));
    const int max_it = gm / GS;        // max(|g|)/GS == max(|g|/GS)

    // --- this row's parameters ---
    const int gv    = g[b];
    const int sign  = gv > 0 ? 1 : (gv < 0 ? -1 : 0);
    const int a     = iabs(gv);
    const int iters = a / GS;
    const int rem   = a % GS;

    float maxk[KK], idk[KK], fink[KK];
    const float* mk = kernels + (size_t)(sign * GS + GS) * KK;
    const float* ik = kernels + (size_t)GS * KK;
    const float* fk = kernels + (size_t)(rem * sign + GS) * KK;
#pragma unroll
    for (int j = 0; j < KK; ++j) { maxk[j] = mk[j]; idk[j] = ik[j]; fink[j] = fk[j]; }

    // --- compose effective 17-tap kernel (polynomial product of 4 stages) ---
    float e[EFF], ne[EFF];
#pragma unroll
    for (int m = 0; m < EFF; ++m) e[m] = 0.f;
    e[0] = 1.f;
    int len = 1;
    for (int i = 0; i < MAXIT; ++i) {
        float kk5[KK];
        if (i < iters) {
#pragma unroll
            for (int j = 0; j < KK; ++j) kk5[j] = maxk[j];
        } else if (i < max_it) {
#pragma unroll
            for (int j = 0; j < KK; ++j) kk5[j] = idk[j];
        } else {
#pragma unroll
            for (int j = 0; j < KK; ++j) kk5[j] = (j == (KK - 1) / 2) ? 1.f : 0.f;
        }
#pragma unroll
        for (int m = 0; m < EFF; ++m) ne[m] = 0.f;
        for (int m = 0; m < len; ++m)
#pragma unroll
            for (int j = 0; j < KK; ++j) ne[m + j] += e[m] * kk5[j];
        len += KK - 1;
#pragma unroll
        for (int m = 0; m < EFF; ++m) e[m] = ne[m];
    }
#pragma unroll
    for (int m = 0; m < EFF; ++m) ne[m] = 0.f;
    for (int m = 0; m < len; ++m)
#pragma unroll
        for (int j = 0; j < KK; ++j) ne[m + j] += e[m] * fink[j];
#pragma unroll
    for (int m = 0; m < EFF; ++m) e[m] = ne[m];

    // --- conv: 8 float4 outputs per thread, direct global reads (L1/L2) ---
    const float4* xr   = (const float4*)(x + (size_t)b * DD);
    vf4*          outr = (vf4*)(out + (size_t)b * DD);
#pragma unroll
    for (int jb = 0; jb < D4 / 256; ++jb) {
        const int v = jb * 256 + t;          // output float4 index; d0 = 4*v
        float f[EFF + 3];                    // inputs x[d0-8 .. d0+11]
#pragma unroll
        for (int q = 0; q < 5; ++q) {
            unsigned idx = (unsigned)(v - 2 + q) & (D4 - 1);   // circular wrap
            float4 val = xr[idx];
            f[q * 4 + 0] = val.x; f[q * 4 + 1] = val.y;
            f[q * 4 + 2] = val.z; f[q * 4 + 3] = val.w;
        }
        float oc[4];
#pragma unroll
        for (int c = 0; c < 4; ++c) {
            float s = 0.f;
#pragma unroll
            for (int m = 0; m < EFF; ++m) s += e[m] * f[c + m];
            oc[c] = s;
        }
        vf4 o;
        o.x = oc[0]; o.y = oc[1]; o.z = oc[2]; o.w = oc[3];
        __builtin_nontemporal_store(o, outr + v);
    }
}

// ---------------------------------------------------------------------------
extern "C" void kernel_launch(void* const* d_in, const int* in_sizes, int n_in,
                              void* d_out, int out_size, void* d_ws, size_t ws_size,
                              hipStream_t stream) {
    const float* x       = (const float*)d_in[0];
    const int*   g       = (const int*)d_in[1];
    const float* kernels = (const float*)d_in[2];
    float*       out     = (float*)d_out;

    k_fused<<<BB, 256, 0, stream>>>(x, g, kernels, out);
}

// Round 4
// 236.711 us; speedup vs baseline: 1.1878x; 1.1878x over previous
//
#include <hip/hip_runtime.h>

// Problem constants (match reference)
#define BB 4096
#define DD 8192
#define KK 5
#define GS 40
#define MAXIT 3
#define EFF 17              // 4*(KK-1)+1 composed taps
#define CHUNK 2048          // floats per block
#define C4 (CHUNK/4)        // 512 f4 per chunk
#define DF4 (DD/4)          // 2048 f4 per row

typedef float vf4 __attribute__((ext_vector_type(4)));

__device__ __forceinline__ int iabs(int a) { return a < 0 ? -a : a; }

// ---------------------------------------------------------------------------
// Kernel 1: max_it = max(|g|)/GS -> ws[0]
// ---------------------------------------------------------------------------
__global__ __launch_bounds__(256) void k_max_it(const int* __restrict__ g,
                                                int* __restrict__ ws) {
    __shared__ int red[256];
    int t = threadIdx.x;
    int m = 0;
    for (int i = t; i < BB; i += 256) m = max(m, iabs(g[i]));
    red[t] = m;
    __syncthreads();
    for (int s = 128; s > 0; s >>= 1) {
        if (t < s) red[t] = max(red[t], red[t + s]);
        __syncthreads();
    }
    if (t == 0) ws[0] = red[0] / GS;
}

// ---------------------------------------------------------------------------
// Kernel 2: one block per 2048-float chunk of a row (4 chunks/row).
// LDS = chunk + 8-float halo each side (8.25 KB) -> occupancy wave-capped.
// Stage coalesced f4, compose effective 17-tap kernel in regs (overlaps
// staging latency), compute from LDS with interleaved f4 assignment
// (lane stride 16 B = conflict-minimal b128 pattern), NT f4 stores.
// ---------------------------------------------------------------------------
__global__ __launch_bounds__(256) void k_conv(const float* __restrict__ x,
                                              const int* __restrict__ g,
                                              const float* __restrict__ kernels,
                                              const int* __restrict__ ws,
                                              float* __restrict__ out) {
    __shared__ float lds[CHUNK + 16];          // [0..1]=left halo f4, [2..513]=chunk, [514..515]=right halo
    float4* ldsv = (float4*)lds;

    const int bi   = blockIdx.x;
    const int b    = bi >> 2;                  // row
    const int ch   = bi & 3;                   // chunk within row
    const int t    = threadIdx.x;
    const int c0f4 = ch * C4;                  // chunk start, f4 units

    const float4* xr = (const float4*)(x + (size_t)b * DD);

    // --- stage: 2 f4 per thread, coalesced; threads 0/1 add halos ---
    ldsv[2 + t]       = xr[c0f4 + t];
    ldsv[2 + t + 256] = xr[c0f4 + t + 256];
    if (t == 0) {
        ldsv[0] = xr[(c0f4 - 2) & (DF4 - 1)];
        ldsv[1] = xr[(c0f4 - 1) & (DF4 - 1)];
    } else if (t == 1) {
        ldsv[514] = xr[(c0f4 + C4)     & (DF4 - 1)];
        ldsv[515] = xr[(c0f4 + C4 + 1) & (DF4 - 1)];
    }

    // --- per-row parameters + effective-kernel composition (pre-barrier) ---
    const int gv    = g[b];
    const int sign  = gv > 0 ? 1 : (gv < 0 ? -1 : 0);
    const int a     = iabs(gv);
    const int iters = a / GS;
    const int rem   = a % GS;
    const int max_it = ws[0];

    float maxk[KK], idk[KK], fink[KK];
    const float* mk = kernels + (size_t)(sign * GS + GS) * KK;
    const float* ik = kernels + (size_t)GS * KK;
    const float* fk = kernels + (size_t)(rem * sign + GS) * KK;
#pragma unroll
    for (int j = 0; j < KK; ++j) { maxk[j] = mk[j]; idk[j] = ik[j]; fink[j] = fk[j]; }

    float e[EFF], ne[EFF];
#pragma unroll
    for (int m = 0; m < EFF; ++m) e[m] = 0.f;
    e[0] = 1.f;
    int len = 1;
    for (int i = 0; i < MAXIT; ++i) {
        float kk5[KK];
        if (i < iters) {
#pragma unroll
            for (int j = 0; j < KK; ++j) kk5[j] = maxk[j];
        } else if (i < max_it) {
#pragma unroll
            for (int j = 0; j < KK; ++j) kk5[j] = idk[j];
        } else {
#pragma unroll
            for (int j = 0; j < KK; ++j) kk5[j] = (j == (KK - 1) / 2) ? 1.f : 0.f;
        }
#pragma unroll
        for (int m = 0; m < EFF; ++m) ne[m] = 0.f;
        for (int m = 0; m < len; ++m)
#pragma unroll
            for (int j = 0; j < KK; ++j) ne[m + j] += e[m] * kk5[j];
        len += KK - 1;
#pragma unroll
        for (int m = 0; m < EFF; ++m) e[m] = ne[m];
    }
#pragma unroll
    for (int m = 0; m < EFF; ++m) ne[m] = 0.f;
    for (int m = 0; m < len; ++m)
#pragma unroll
        for (int j = 0; j < KK; ++j) ne[m + j] += e[m] * fink[j];
#pragma unroll
    for (int m = 0; m < EFF; ++m) e[m] = ne[m];

    __syncthreads();

    // --- compute: 2 f4 outputs per thread, interleaved (lane stride 16 B) ---
    vf4* outr = (vf4*)(out + (size_t)b * DD);
#pragma unroll
    for (int jb = 0; jb < 2; ++jb) {
        const int v = jb * 256 + t;            // f4 idx within chunk [0,512)
        float f[EFF + 3];                      // x[d0-8 .. d0+11], d0 = 4v local
#pragma unroll
        for (int q = 0; q < 5; ++q) {
            float4 val = ldsv[v + q];          // halo shift: ldsv[2] == chunk start
            f[q * 4 + 0] = val.x; f[q * 4 + 1] = val.y;
            f[q * 4 + 2] = val.z; f[q * 4 + 3] = val.w;
        }
        float oc[4];
#pragma unroll
        for (int c = 0; c < 4; ++c) {
            float s = 0.f;
#pragma unroll
            for (int m = 0; m < EFF; ++m) s += e[m] * f[c + m];
            oc[c] = s;
        }
        vf4 o;
        o.x = oc[0]; o.y = oc[1]; o.z = oc[2]; o.w = oc[3];
        __builtin_nontemporal_store(o, outr + c0f4 + v);
    }
}

// ---------------------------------------------------------------------------
extern "C" void kernel_launch(void* const* d_in, const int* in_sizes, int n_in,
                              void* d_out, int out_size, void* d_ws, size_t ws_size,
                              hipStream_t stream) {
    const float* x       = (const float*)d_in[0];
    const int*   g       = (const int*)d_in[1];
    const float* kernels = (const float*)d_in[2];
    float*       out     = (float*)d_out;
    int*         ws      = (int*)d_ws;

    k_max_it<<<1, 256, 0, stream>>>(g, ws);
    k_conv<<<BB * (DD / CHUNK), 256, 0, stream>>>(x, g, kernels, ws, out);
}